// Round 11
// baseline (45.323 us; speedup 1.0000x reference)
//
#include <hip/hip_runtime.h>

#define NUM_POINTS 2048
#define FEAT 512
#define BATCH 32

using v8s = __attribute__((ext_vector_type(8))) short;
using v4u = __attribute__((ext_vector_type(4))) unsigned;
using v4f = __attribute__((ext_vector_type(4))) float;

// Pack bf16(x)|bf16(y) by truncation: one v_perm_b32.
static __device__ __forceinline__ unsigned pk_trunc(float x, float y) {
  return __builtin_amdgcn_perm(__float_as_uint(y), __float_as_uint(x), 0x07060302u);
}

// Contiguous-stream + hi-occupancy + overlapped design.
// One position per block; 4 waves = 4 output quadrants (mt=w>>1, nt=w&1).
// K split in two halves; each half's 32KB fp32 slab is read cooperatively
// in PURE 1KB-contiguous wave-instrs (copy-kernel pattern), trunc-converted,
// and written to a 16KB bf16 LDS tile (XOR-swizzled: 16B chunk ^= row&7 ->
// <=2-way conflicts). Half1's global loads are issued BEFORE half0's
// consume (T14): HBM latency hides under MFMA+ds_read.
// B-fragments come straight from glf: lane l of wave nt needs exactly
// glf[row = nt*16 + (l&15)][ks*32 + (l>>4)*8 ..+8] -> contiguous 32B loads,
// no shuffle, no prepack kernel.
__global__ void __launch_bounds__(256, 4) fcdec_stream(
    const float* __restrict__ glf,
    const float* __restrict__ W1, const float* __restrict__ b1,
    const float* __restrict__ W2, const float* __restrict__ b2,
    const float* __restrict__ W3, const float* __restrict__ b3,
    float* __restrict__ out) {
  __shared__ short Abf[2][32 * 256];   // 2 x 16KB swizzled bf16 half-tiles
  __shared__ float h1s[32][33];
  __shared__ float h2s[8][33];

  const int t = threadIdx.x;
  const int w = t >> 6;
  const int l = t & 63;
  const int p = blockIdx.x;
  const int mt = w >> 1, nt = w & 1;
  const int lrow = l & 15;
  const int g = l >> 4;                       // 0..3

  const float* A0 = W1 + (size_t)p * (32 * FEAT);
  const float* Grow = glf + (nt * 16 + lrow) * FEAT + (g << 3);
  const int q_r = t >> 6;                     // base row contribution of t (i*4+w)
  const int q_fk = l;                         // fk = lane (64 chunks per row)

  // ---- prologue: B half0 (L2-class) first, then stage half0 (HBM) ----
  float4 gb[16];
  #pragma unroll
  for (int ksl = 0; ksl < 8; ++ksl) {
    gb[2 * ksl]     = *(const float4*)(Grow + ksl * 32);
    gb[2 * ksl + 1] = *(const float4*)(Grow + ksl * 32 + 4);
  }
  float4 S[8];
  #pragma unroll
  for (int i = 0; i < 8; ++i) {
    const int r = i * 4 + q_r;                // wave-uniform row
    S[i] = *(const float4*)(A0 + r * FEAT + (q_fk << 2));   // 1KB contig/instr
  }
  v8s bvA[8];
  #pragma unroll
  for (int ksl = 0; ksl < 8; ++ksl) {
    v4u u;
    u[0] = pk_trunc(gb[2 * ksl].x, gb[2 * ksl].y);
    u[1] = pk_trunc(gb[2 * ksl].z, gb[2 * ksl].w);
    u[2] = pk_trunc(gb[2 * ksl + 1].x, gb[2 * ksl + 1].y);
    u[3] = pk_trunc(gb[2 * ksl + 1].z, gb[2 * ksl + 1].w);
    bvA[ksl] = __builtin_bit_cast(v8s, u);
  }
  #pragma unroll
  for (int i = 0; i < 8; ++i) {
    const int r = i * 4 + q_r;
    const int c = q_fk >> 1;
    uint2 pk;
    pk.x = pk_trunc(S[i].x, S[i].y);
    pk.y = pk_trunc(S[i].z, S[i].w);
    *(uint2*)&Abf[0][r * 256 + (((c ^ (r & 7)) << 3)) + ((q_fk & 1) << 2)] = pk;
  }
  __syncthreads();

  // ---- issue half1: B loads first (older), then 1KB-contig stage loads ----
  #pragma unroll
  for (int ksl = 0; ksl < 8; ++ksl) {
    gb[2 * ksl]     = *(const float4*)(Grow + 256 + ksl * 32);
    gb[2 * ksl + 1] = *(const float4*)(Grow + 256 + ksl * 32 + 4);
  }
  float4 S1[8];
  #pragma unroll
  for (int i = 0; i < 8; ++i) {
    const int r = i * 4 + q_r;
    S1[i] = *(const float4*)(A0 + r * FEAT + 256 + (q_fk << 2));
  }
  // convert B half1 early (waits only on gb; S1 stays in flight)
  v8s bvB[8];
  #pragma unroll
  for (int ksl = 0; ksl < 8; ++ksl) {
    v4u u;
    u[0] = pk_trunc(gb[2 * ksl].x, gb[2 * ksl].y);
    u[1] = pk_trunc(gb[2 * ksl].z, gb[2 * ksl].w);
    u[2] = pk_trunc(gb[2 * ksl + 1].x, gb[2 * ksl + 1].y);
    u[3] = pk_trunc(gb[2 * ksl + 1].z, gb[2 * ksl + 1].w);
    bvB[ksl] = __builtin_bit_cast(v8s, u);
  }

  // ---- consume half0 from LDS (lgkm only; S1 in flight on vmcnt) ----
  const int arow = mt * 16 + lrow;
  const int sw = arow & 7;
  v4f acc = {};
  #pragma unroll
  for (int ksl = 0; ksl < 8; ++ksl) {
    const int c = (ksl << 2) + g;
    const v8s a = *(const v8s*)&Abf[0][arow * 256 + ((c ^ sw) << 3)];
    acc = __builtin_amdgcn_mfma_f32_16x16x32_bf16(a, bvA[ksl], acc, 0, 0, 0);
  }

  // ---- write stage half1 (waits S1; Abf[1] is virgin -> no barrier before)
  #pragma unroll
  for (int i = 0; i < 8; ++i) {
    const int r = i * 4 + q_r;
    const int c = q_fk >> 1;
    uint2 pk;
    pk.x = pk_trunc(S1[i].x, S1[i].y);
    pk.y = pk_trunc(S1[i].z, S1[i].w);
    *(uint2*)&Abf[1][r * 256 + (((c ^ (r & 7)) << 3)) + ((q_fk & 1) << 2)] = pk;
  }
  __syncthreads();

  // ---- consume half1 ----
  #pragma unroll
  for (int ksl = 0; ksl < 8; ++ksl) {
    const int c = (ksl << 2) + g;
    const v8s a = *(const v8s*)&Abf[1][arow * 256 + ((c ^ sw) << 3)];
    acc = __builtin_amdgcn_mfma_f32_16x16x32_bf16(a, bvB[ksl], acc, 0, 0, 0);
  }

  // ---- h1 = acc + b1 -> LDS. C/D: lane l holds C[row=g*4+r][col=lrow] ----
  #pragma unroll
  for (int r4 = 0; r4 < 4; ++r4) {
    const int o = mt * 16 + (g << 2) + r4;
    h1s[o][nt * 16 + lrow] = acc[r4] + b1[p * 32 + o];
  }
  __syncthreads();

  // ---- layer 2: 256 threads = 8 outs x 32 batches ----
  {
    const int o8 = t >> 5;
    const int b = t & 31;
    float s2 = b2[p * 8 + o8];
    const float* w2 = W2 + (size_t)(p * 8 + o8) * 32;
    #pragma unroll
    for (int i = 0; i < 32; ++i) s2 += w2[i] * h1s[i][b];
    h2s[o8][b] = s2;
  }
  __syncthreads();

  // ---- layer 3: 32 threads, 3 outputs each ----
  if (t < 32) {
    const int b = t;
    #pragma unroll
    for (int c = 0; c < 3; ++c) {
      float s3 = b3[p * 3 + c];
      const float* w3 = W3 + (size_t)(p * 3 + c) * 8;
      #pragma unroll
      for (int j = 0; j < 8; ++j) s3 += w3[j] * h2s[j][b];
      out[(size_t)(b * 3 + c) * NUM_POINTS + p] = s3;
    }
  }
}

extern "C" void kernel_launch(void* const* d_in, const int* in_sizes, int n_in,
                              void* d_out, int out_size, void* d_ws, size_t ws_size,
                              hipStream_t stream) {
  const float* glf = (const float*)d_in[0];
  const float* W1  = (const float*)d_in[1];
  const float* b1  = (const float*)d_in[2];
  const float* W2  = (const float*)d_in[3];
  const float* b2  = (const float*)d_in[4];
  const float* W3  = (const float*)d_in[5];
  const float* b3  = (const float*)d_in[6];
  float* out = (float*)d_out;

  hipLaunchKernelGGL(fcdec_stream, dim3(NUM_POINTS), dim3(256), 0, stream,
                     glf, W1, b1, W2, b2, W3, b3, out);
}

// Round 13
// 33.051 us; speedup vs baseline: 1.3713x; 1.3713x over previous
//
#include <hip/hip_runtime.h>

#define NUM_POINTS 2048
#define FEAT 512
#define BATCH 32
#define PAIRS 2               // 2 position-pairs = 4 positions per block
#define POS_PER_BLOCK 4

using v8s = __attribute__((ext_vector_type(8))) short;
using v4u = __attribute__((ext_vector_type(4))) unsigned;
using v4f = __attribute__((ext_vector_type(4))) float;

// Pack bf16(x) (low16) | bf16(y) (high16) by truncation: one v_perm_b32.
static __device__ __forceinline__ unsigned pk_trunc(float x, float y) {
  return __builtin_amdgcn_perm(__float_as_uint(y), __float_as_uint(x), 0x07060302u);
}

// Non-temporal dwordx4 load via native vector type (builtin rejects
// HIP_vector_type structs).
static __device__ __forceinline__ v4f nt_load4(const float* p) {
  return __builtin_nontemporal_load((const v4f*)p);
}

// R10 persistent-block kernel, single change: W1 stream loads are
// NON-TEMPORAL (skip cache allocation). Tests whether L2/L3 fill-allocation
// occupancy is part of the ~4.5 TB/s demand-read cap.
__global__ void __launch_bounds__(256, 2) fcdec_persist(
    const float* __restrict__ glf,
    const float* __restrict__ W1, const float* __restrict__ b1,
    const float* __restrict__ W2, const float* __restrict__ b2,
    const float* __restrict__ W3, const float* __restrict__ b3,
    float* __restrict__ out) {
  __shared__ short bfrag[16 * 2 * 64 * 8];          // 32 KB, lives whole kernel
  __shared__ float h1s[POS_PER_BLOCK][32][33];      // 16.9 KB

  const int t = threadIdx.x;
  const int w = t >> 6;
  const int l = t & 63;
  const int lp = w >> 1;            // position-within-pair
  const int mt = w & 1;             // M-split
  const int lrow = l & 15;
  const int lk = (l >> 4) << 3;     // 0,8,16,24
  const int pbase = blockIdx.x * POS_PER_BLOCK;

  // Per-pair A row base pointers (this wave's 16-row slab)
  const float* Ap[PAIRS];
  #pragma unroll
  for (int pr = 0; pr < PAIRS; ++pr)
    Ap[pr] = W1 + ((size_t)(pbase + 2 * pr + lp) * 32u + mt * 16 + lrow) * FEAT + lk;

  // ---- 1: glf loads first (retire earliest under in-order vmcnt) ----
  float4 g[16];
  #pragma unroll
  for (int rep = 0; rep < 16; ++rep) {
    const int c = rep * 256 + t;
    const int b = c >> 7;
    const int k0 = (c & 127) << 2;
    g[rep] = *(const float4*)(glf + b * FEAT + k0);
  }

  // ---- 2: prologue: issue steps 0..7 (16 dwordx4 in flight, NT) ----
  v4f fa[8], fb[8];
  #pragma unroll
  for (int s = 0; s < 8; ++s) {
    fa[s] = nt_load4(Ap[0] + s * 32);
    fb[s] = nt_load4(Ap[0] + s * 32 + 4);
  }

  // ---- 3: build B fragments in LDS once (overlaps A flight) ----
  // frag layout: lane l holds B[k=ks*32+(l>>4)*8+j][col=nt*16+(l&15)]
  #pragma unroll
  for (int rep = 0; rep < 16; ++rep) {
    const int c = rep * 256 + t;
    const int b = c >> 7;
    const int k0 = (c & 127) << 2;
    const int ks = k0 >> 5;
    const int gsel = (k0 >> 3) & 3;
    const int j0 = k0 & 7;          // 0 or 4
    const int nt = b >> 4;
    const int ll = gsel * 16 + (b & 15);
    uint2 pk;
    pk.x = pk_trunc(g[rep].x, g[rep].y);
    pk.y = pk_trunc(g[rep].z, g[rep].w);
    *(uint2*)(bfrag + (((ks * 2 + nt) * 64 + ll) << 3) + j0) = pk;
  }
  __syncthreads();

  // ---- 4: seamless main loop: 32 steps, rolling 8-deep window (NT refill) ----
  v4f acc[PAIRS][2] = {};
  #pragma unroll
  for (int s = 0; s < PAIRS * 16; ++s) {
    const int pr = s >> 4;
    const int ks = s & 15;
    const v4f c0 = fa[s & 7];
    const v4f c1 = fb[s & 7];
    if (s + 8 < PAIRS * 16) {       // static under full unroll
      const int s2 = s + 8;
      fa[s & 7] = nt_load4(Ap[s2 >> 4] + (s2 & 15) * 32);
      fb[s & 7] = nt_load4(Ap[s2 >> 4] + (s2 & 15) * 32 + 4);
    }
    v4u au;
    au[0] = pk_trunc(c0[0], c0[1]);
    au[1] = pk_trunc(c0[2], c0[3]);
    au[2] = pk_trunc(c1[0], c1[1]);
    au[3] = pk_trunc(c1[2], c1[3]);
    const v8s a = __builtin_bit_cast(v8s, au);
    const v8s bv0 = *(const v8s*)(bfrag + (((ks * 2 + 0) * 64 + l) << 3));
    const v8s bv1 = *(const v8s*)(bfrag + (((ks * 2 + 1) * 64 + l) << 3));
    acc[pr][0] = __builtin_amdgcn_mfma_f32_16x16x32_bf16(a, bv0, acc[pr][0], 0, 0, 0);
    acc[pr][1] = __builtin_amdgcn_mfma_f32_16x16x32_bf16(a, bv1, acc[pr][1], 0, 0, 0);
  }

  // ---- 5: h1 -> LDS for all 4 positions. C/D: row=(l>>4)*4+r, col=l&15 ----
  #pragma unroll
  for (int pr = 0; pr < PAIRS; ++pr) {
    const int pg = pbase + 2 * pr + lp;
    #pragma unroll
    for (int r = 0; r < 4; ++r) {
      const int o = mt * 16 + ((l >> 4) << 2) + r;
      const float bb = b1[pg * 32 + o];
      h1s[2 * pr + lp][o][lrow] = acc[pr][0][r] + bb;
      h1s[2 * pr + lp][o][16 + lrow] = acc[pr][1][r] + bb;
    }
  }
  __syncthreads();

  // ---- 6: layers 2+3 fp32: one thread per (position, batch) ----
  if (t < POS_PER_BLOCK * BATCH) {
    const int tp = t >> 5;          // 0..3
    const int b = t & 31;
    const int pg = pbase + tp;
    float h2[8];
    #pragma unroll
    for (int o8 = 0; o8 < 8; ++o8) {
      float s = b2[pg * 8 + o8];
      const float* w2 = W2 + (size_t)(pg * 8 + o8) * 32;
      #pragma unroll
      for (int i = 0; i < 32; ++i) s += w2[i] * h1s[tp][i][b];
      h2[o8] = s;
    }
    #pragma unroll
    for (int c = 0; c < 3; ++c) {
      float s = b3[pg * 3 + c];
      const float* w3 = W3 + (size_t)(pg * 3 + c) * 8;
      #pragma unroll
      for (int j = 0; j < 8; ++j) s += w3[j] * h2[j];
      out[(size_t)(b * 3 + c) * NUM_POINTS + pg] = s;
    }
  }
}

extern "C" void kernel_launch(void* const* d_in, const int* in_sizes, int n_in,
                              void* d_out, int out_size, void* d_ws, size_t ws_size,
                              hipStream_t stream) {
  const float* glf = (const float*)d_in[0];
  const float* W1  = (const float*)d_in[1];
  const float* b1  = (const float*)d_in[2];
  const float* W2  = (const float*)d_in[3];
  const float* b2  = (const float*)d_in[4];
  const float* W3  = (const float*)d_in[5];
  const float* b3  = (const float*)d_in[6];
  float* out = (float*)d_out;

  hipLaunchKernelGGL(fcdec_persist, dim3(NUM_POINTS / POS_PER_BLOCK), dim3(256), 0, stream,
                     glf, W1, b1, W2, b2, W3, b3, out);
}

// Round 14
// 30.151 us; speedup vs baseline: 1.5032x; 1.0962x over previous
//
#include <hip/hip_runtime.h>

#define NUM_POINTS 2048
#define FEAT 512
#define BATCH 32
#define PAIRS 2               // 2 position-pairs = 4 positions per block
#define POS_PER_BLOCK 4

using v8s = __attribute__((ext_vector_type(8))) short;
using v4u = __attribute__((ext_vector_type(4))) unsigned;
using v4f = __attribute__((ext_vector_type(4))) float;

// Pack bf16(x) (low16) | bf16(y) (high16) by truncation: one v_perm_b32.
static __device__ __forceinline__ unsigned pk_trunc(float x, float y) {
  return __builtin_amdgcn_perm(__float_as_uint(y), __float_as_uint(x), 0x07060302u);
}

// FINAL (R10, proven 30.3us): persistent blocks — 512 blocks (2/CU, zero
// turnover), 4 positions each. Rolling 8-deep A-prefetch spans the whole
// 32-step K-stream (2 pairs x 16 ks) with no drain at pair boundaries.
// bfrag built once per block; accumulators for all 4 positions in registers;
// single epilogue. W1 stream (134MB, cold each replay) is the mandatory
// traffic; measured demand-read service ~4.7 TB/s sets the ~30us floor.
__global__ void __launch_bounds__(256, 2) fcdec_persist(
    const float* __restrict__ glf,
    const float* __restrict__ W1, const float* __restrict__ b1,
    const float* __restrict__ W2, const float* __restrict__ b2,
    const float* __restrict__ W3, const float* __restrict__ b3,
    float* __restrict__ out) {
  __shared__ short bfrag[16 * 2 * 64 * 8];          // 32 KB, lives whole kernel
  __shared__ float h1s[POS_PER_BLOCK][32][33];      // 16.9 KB

  const int t = threadIdx.x;
  const int w = t >> 6;
  const int l = t & 63;
  const int lp = w >> 1;            // position-within-pair
  const int mt = w & 1;             // M-split
  const int lrow = l & 15;
  const int lk = (l >> 4) << 3;     // 0,8,16,24
  const int pbase = blockIdx.x * POS_PER_BLOCK;

  // Per-pair A row base pointers (this wave's 16-row slab)
  const float* Ap[PAIRS];
  #pragma unroll
  for (int pr = 0; pr < PAIRS; ++pr)
    Ap[pr] = W1 + ((size_t)(pbase + 2 * pr + lp) * 32u + mt * 16 + lrow) * FEAT + lk;

  // ---- 1: glf loads first (retire earliest under in-order vmcnt) ----
  float4 g[16];
  #pragma unroll
  for (int rep = 0; rep < 16; ++rep) {
    const int c = rep * 256 + t;
    const int b = c >> 7;
    const int k0 = (c & 127) << 2;
    g[rep] = *(const float4*)(glf + b * FEAT + k0);
  }

  // ---- 2: prologue: issue steps 0..7 (16 dwordx4 in flight) ----
  float4 fa[8], fb[8];
  #pragma unroll
  for (int s = 0; s < 8; ++s) {
    fa[s] = *(const float4*)(Ap[0] + s * 32);
    fb[s] = *(const float4*)(Ap[0] + s * 32 + 4);
  }

  // ---- 3: build B fragments in LDS once (overlaps A flight) ----
  // frag layout: lane l holds B[k=ks*32+(l>>4)*8+j][col=nt*16+(l&15)]
  #pragma unroll
  for (int rep = 0; rep < 16; ++rep) {
    const int c = rep * 256 + t;
    const int b = c >> 7;
    const int k0 = (c & 127) << 2;
    const int ks = k0 >> 5;
    const int gsel = (k0 >> 3) & 3;
    const int j0 = k0 & 7;          // 0 or 4
    const int nt = b >> 4;
    const int ll = gsel * 16 + (b & 15);
    uint2 pk;
    pk.x = pk_trunc(g[rep].x, g[rep].y);
    pk.y = pk_trunc(g[rep].z, g[rep].w);
    *(uint2*)(bfrag + (((ks * 2 + nt) * 64 + ll) << 3) + j0) = pk;
  }
  __syncthreads();

  // ---- 4: seamless main loop: 32 steps, rolling 8-deep window ----
  v4f acc[PAIRS][2] = {};
  #pragma unroll
  for (int s = 0; s < PAIRS * 16; ++s) {
    const int pr = s >> 4;
    const int ks = s & 15;
    const float4 c0 = fa[s & 7];
    const float4 c1 = fb[s & 7];
    if (s + 8 < PAIRS * 16) {       // static under full unroll
      const int s2 = s + 8;
      fa[s & 7] = *(const float4*)(Ap[s2 >> 4] + (s2 & 15) * 32);
      fb[s & 7] = *(const float4*)(Ap[s2 >> 4] + (s2 & 15) * 32 + 4);
    }
    v4u au;
    au[0] = pk_trunc(c0.x, c0.y);
    au[1] = pk_trunc(c0.z, c0.w);
    au[2] = pk_trunc(c1.x, c1.y);
    au[3] = pk_trunc(c1.z, c1.w);
    const v8s a = __builtin_bit_cast(v8s, au);
    const v8s bv0 = *(const v8s*)(bfrag + (((ks * 2 + 0) * 64 + l) << 3));
    const v8s bv1 = *(const v8s*)(bfrag + (((ks * 2 + 1) * 64 + l) << 3));
    acc[pr][0] = __builtin_amdgcn_mfma_f32_16x16x32_bf16(a, bv0, acc[pr][0], 0, 0, 0);
    acc[pr][1] = __builtin_amdgcn_mfma_f32_16x16x32_bf16(a, bv1, acc[pr][1], 0, 0, 0);
  }

  // ---- 5: h1 -> LDS for all 4 positions. C/D: row=(l>>4)*4+r, col=l&15 ----
  #pragma unroll
  for (int pr = 0; pr < PAIRS; ++pr) {
    const int pg = pbase + 2 * pr + lp;
    #pragma unroll
    for (int r = 0; r < 4; ++r) {
      const int o = mt * 16 + ((l >> 4) << 2) + r;
      const float bb = b1[pg * 32 + o];
      h1s[2 * pr + lp][o][lrow] = acc[pr][0][r] + bb;
      h1s[2 * pr + lp][o][16 + lrow] = acc[pr][1][r] + bb;
    }
  }
  __syncthreads();

  // ---- 6: layers 2+3 fp32: one thread per (position, batch) ----
  if (t < POS_PER_BLOCK * BATCH) {
    const int tp = t >> 5;          // 0..3
    const int b = t & 31;
    const int pg = pbase + tp;
    float h2[8];
    #pragma unroll
    for (int o8 = 0; o8 < 8; ++o8) {
      float s = b2[pg * 8 + o8];
      const float* w2 = W2 + (size_t)(pg * 8 + o8) * 32;
      #pragma unroll
      for (int i = 0; i < 32; ++i) s += w2[i] * h1s[tp][i][b];
      h2[o8] = s;
    }
    #pragma unroll
    for (int c = 0; c < 3; ++c) {
      float s = b3[pg * 3 + c];
      const float* w3 = W3 + (size_t)(pg * 3 + c) * 8;
      #pragma unroll
      for (int j = 0; j < 8; ++j) s += w3[j] * h2[j];
      out[(size_t)(b * 3 + c) * NUM_POINTS + pg] = s;
    }
  }
}

extern "C" void kernel_launch(void* const* d_in, const int* in_sizes, int n_in,
                              void* d_out, int out_size, void* d_ws, size_t ws_size,
                              hipStream_t stream) {
  const float* glf = (const float*)d_in[0];
  const float* W1  = (const float*)d_in[1];
  const float* b1  = (const float*)d_in[2];
  const float* W2  = (const float*)d_in[3];
  const float* b2  = (const float*)d_in[4];
  const float* W3  = (const float*)d_in[5];
  const float* b3  = (const float*)d_in[6];
  float* out = (float*)d_out;

  hipLaunchKernelGGL(fcdec_persist, dim3(NUM_POINTS / POS_PER_BLOCK), dim3(256), 0, stream,
                     glf, W1, b1, W2, b2, W3, b3, out);
}